// Round 10
// baseline (233.411 us; speedup 1.0000x reference)
//
#include <hip/hip_runtime.h>
#include <stdint.h>

typedef unsigned short u16;
typedef unsigned char u8;
typedef __attribute__((ext_vector_type(8))) short bf16x8;
typedef __attribute__((ext_vector_type(4))) float f32x4;
typedef __attribute__((ext_vector_type(2))) float f32x2;
typedef __attribute__((ext_vector_type(8))) unsigned short u16x8;

#define N_NODES 100000
#define N_EDGES 500000
#define EMBED   256
#define PDIM    768   // fp8 bytes: X[0:256) Y[256:512) Xa[512:640) Ya[640:768)
#define NG16    (N_EDGES / 16)   // 31250 wave-groups of 16 edges
#define NTILES  4692             // 782 m-tiles * 6 n-tiles
#define TPX     587              // ceil(4692/8) tiles per XCD

__device__ __forceinline__ u16 f2bf(float f) {
    unsigned int x; __builtin_memcpy(&x, &f, 4);
    unsigned int r = (x + 0x7fffu + ((x >> 16) & 1u)) >> 16;
    return (u16)r;
}
__device__ __forceinline__ unsigned int pack_bf2(float lo, float hi) {
    unsigned int a, b;
    __builtin_memcpy(&a, &lo, 4); __builtin_memcpy(&b, &hi, 4);
    return (a >> 16) | (b & 0xffff0000u);   // truncation (matches r9 numerics)
}

#define GLOBAL_AS __attribute__((address_space(1)))
#define LDS_AS    __attribute__((address_space(3)))
__device__ __forceinline__ void gload_lds16(const void* g, void* l) {
    __builtin_amdgcn_global_load_lds((const GLOBAL_AS uint32_t*)g,
                                     (LDS_AS uint32_t*)l, 16, 0, 0);
}

// ---------------- K0b: build WcatT [768][256] bf16 ----------------
__global__ __launch_bounds__(256) void k_build_wcat(const float* __restrict__ W1,
                                                    const float* __restrict__ Wa1,
                                                    u16* __restrict__ WcatT) {
    int c = blockIdx.x;
    int k = threadIdx.x;
    float v;
    if (c < 256)      v = W1[(size_t)k * 256 + c];
    else if (c < 512) v = W1[(size_t)(256 + k) * 256 + (c - 256)];
    else if (c < 640) v = Wa1[(size_t)k * 128 + (c - 512)];
    else              v = Wa1[(size_t)(256 + k) * 128 + (c - 640)];
    WcatT[(size_t)c * 256 + k] = f2bf(v);
}

// ---------------- K0c: Wa2 -> fp8 B-fragment table [16 frags][64 lanes][8B] ----------------
__global__ __launch_bounds__(64) void k_build_wa2frag(const float* __restrict__ Wa2,
                                                      u8* __restrict__ out) {
    int f = blockIdx.x, l = threadIdx.x;
    int nt = f >> 2, ks = f & 3;
    int j = nt * 16 + (l & 15);
    int kb = ks * 32 + (l >> 4) * 8;
    float v[8];
#pragma unroll
    for (int e = 0; e < 8; e++) v[e] = Wa2[(size_t)(kb + e) * 64 + j];
    unsigned int w0 = __builtin_amdgcn_cvt_pk_fp8_f32(v[0], v[1], 0, false);
    w0 = __builtin_amdgcn_cvt_pk_fp8_f32(v[2], v[3], w0, true);
    unsigned int w1 = __builtin_amdgcn_cvt_pk_fp8_f32(v[4], v[5], 0, false);
    w1 = __builtin_amdgcn_cvt_pk_fp8_f32(v[6], v[7], w1, true);
    uint2 o; o.x = w0; o.y = w1;
    *(uint2*)(out + ((size_t)f * 64 + l) * 8) = o;
}

// ---------------- K1: P[100000][768] fp8 = emb_fp32 @ Wcat (fused convert) ----------------
// A reg-staged: global fp32 -> truncate-pack bf16 in regs -> swizzled ds_write.
// As is 16KB bf16 with row-XOR swizzle ((row&7)<<4) on write AND read ->
// conflict-free. B path and MFMA identical to the proven r6 kernel.
__global__ __launch_bounds__(256) void k_gemm(const float* __restrict__ A,
                                              const u16* __restrict__ BT,
                                              u8* __restrict__ P) {
    __shared__ u16 As[128 * 64];   // bf16, swizzled, 16KB
    __shared__ u16 Bs[128 * 64];   // bf16, linear (gload), 16KB
    int lid = (blockIdx.x & 7) * TPX + (blockIdx.x >> 3);
    if (lid >= NTILES) return;
    int mtile = lid / 6, ntile = lid % 6;
    int m0 = mtile * 128, n0 = ntile * 128;
    int t = threadIdx.x, w = t >> 6, lane = t & 63;
    int wr = (w >> 1) * 64, wc = (w & 1) * 64;

    // A staging assignment: thread t -> row t>>1, k-half t&1 (32 f32 each)
    int arow_s = t >> 1, ahalf = t & 1;
    int ag = m0 + arow_s; if (ag > N_NODES - 1) ag = N_NODES - 1;
    const float* asrc = A + (size_t)ag * 256 + ahalf * 32;
    int abase = arow_s * 128 + ahalf * 64;     // byte offset in As (pre-swizzle)
    int aswz = (arow_s & 7) << 4;

    f32x4 acc[4][4] = {};

    for (int kk = 0; kk < 256; kk += 64) {
        // ---- stage B via gload (linear dest) ----
#pragma unroll
        for (int i = 0; i < 4; i++) {
            int q = w * 4 + i;
            int row = 8 * q + (lane >> 3);
            gload_lds16(BT + (size_t)(n0 + row) * 256 + kk + (lane & 7) * 8,
                        (char*)Bs + q * 1024);
        }
        // ---- stage A: 8x float4 load, pack to bf16, 4x swizzled b128 write ----
        float4 f[8];
#pragma unroll
        for (int j = 0; j < 8; j++) f[j] = *(const float4*)(asrc + kk + j * 4);
#pragma unroll
        for (int j = 0; j < 4; j++) {
            uint4 o;
            o.x = pack_bf2(f[2*j].x, f[2*j].y);
            o.y = pack_bf2(f[2*j].z, f[2*j].w);
            o.z = pack_bf2(f[2*j+1].x, f[2*j+1].y);
            o.w = pack_bf2(f[2*j+1].z, f[2*j+1].w);
            *(uint4*)((char*)As + ((abase + j * 16) ^ aswz)) = o;
        }
        __syncthreads();

        bf16x8 af[4][2], bf[4][2];
#pragma unroll
        for (int ks = 0; ks < 2; ks++) {
#pragma unroll
            for (int m = 0; m < 4; m++) {
                int rr = wr + m * 16 + (lane & 15);
                int abyte = (rr * 128 + ks * 64 + (lane >> 4) * 16) ^ ((rr & 7) << 4);
                af[m][ks] = *(const bf16x8*)((const char*)As + abyte);
            }
#pragma unroll
            for (int n = 0; n < 4; n++)
                bf[n][ks] = *(const bf16x8*)(Bs + (wc + n * 16 + (lane & 15)) * 64 + ks * 32 + (lane >> 4) * 8);
        }
#pragma unroll
        for (int m = 0; m < 4; m++)
#pragma unroll
            for (int n = 0; n < 4; n++)
#pragma unroll
                for (int ks = 0; ks < 2; ks++)
                    acc[m][n] = __builtin_amdgcn_mfma_f32_16x16x32_bf16(af[m][ks], bf[n][ks], acc[m][n], 0, 0, 0);
        __syncthreads();
    }

#pragma unroll
    for (int m = 0; m < 4; m++) {
        int rbase = m0 + wr + m * 16 + (lane >> 4) * 4;
#pragma unroll
        for (int q = 0; q < 4; q++) {
            int row = rbase + q;
            if (row >= N_NODES) continue;
            u8* prow = P + (size_t)row * 768 + n0 + wc + (lane & 15);
#pragma unroll
            for (int n = 0; n < 4; n++) {
                int pk = __builtin_amdgcn_cvt_pk_fp8_f32(acc[m][n][q], acc[m][n][q], 0, false);
                prow[n * 16] = (u8)(pk & 0xff);
            }
        }
    }
}

// ---------------- K2: fused per-edge kernel -- exact round-6 configuration ----------------
__global__ __launch_bounds__(256, 5) void k_edges(const u8* __restrict__ Ptab,
                                                  const u8* __restrict__ wa2t,
                                                  const int* __restrict__ edges,
                                                  const int* __restrict__ army,
                                                  const float* __restrict__ b1,
                                                  const float* __restrict__ W2,
                                                  const float* __restrict__ b2,
                                                  const float* __restrict__ ba1,
                                                  const float* __restrict__ ba2,
                                                  float* __restrict__ out_logits,
                                                  float* __restrict__ out_army) {
    __shared__ u8 wa2s[8192];            // fp8 B-frag table, shared by all waves
    __shared__ u8 HA[4][16 * 128];       // fp8 per-wave, row-XOR swizzled (2KB/wave)
    __shared__ float b1r[4][68], W2r[4][68], ba1r[4][36];

    int t = threadIdx.x, w = t >> 6, lane = t & 63;

    b1r[t >> 6][t & 63] = b1[t];
    W2r[t >> 6][t & 63] = W2[t];
    if (t < 128) ba1r[t >> 5][t & 31] = ba1[t];
    {   // copy 8KB wa2 frag table global->LDS
        uint4* dst = (uint4*)wa2s; const uint4* src = (const uint4*)wa2t;
        dst[t] = src[t]; dst[t + 256] = src[t + 256];
    }
    float b2v = b2[0];
    float ba2v[4];
#pragma unroll
    for (int nt = 0; nt < 4; nt++) ba2v[nt] = ba2[nt * 16 + (lane & 15)];
    __syncthreads();   // once, outside the loop

    char* HAc = (char*)HA[w];
    int e_in_w = lane >> 2, sub = lane & 3;
    int swz = (e_in_w & 7) << 4;
    int gstep = gridDim.x << 2;

    int g = blockIdx.x * 4 + w;
    int2 ev = {0, 0}; int sa = 0, ta = 0;
    if (g < NG16) {
        ev = *(const int2*)(edges + 2 * (g * 16 + e_in_w));
        sa = army[ev.x]; ta = army[ev.y];
    }

    for (; g < NG16; g += gstep) {
        // prefetch next iteration's edge + army (breaks the serial pointer chain)
        int gn = g + gstep;
        int2 evn = ev; int san = sa, tan = ta;
        if (gn < NG16) {
            evn = *(const int2*)(edges + 2 * (gn * 16 + e_in_w));
            san = army[evn.x]; tan = army[evn.y];
        }

        float pen = ((sa <= 2) || (ta >= 3 * sa)) ? 1.0f : 0.0f;
        if (ev.x == ev.y) pen += 100.0f;
        const u8* ps = Ptab + (size_t)ev.x * 768;
        const u8* pt = Ptab + (size_t)ev.y * 768;

        // ---- edge logit over k = sub*64 .. +64 (interleaved load/consume) ----
        float logit = 0.f;
        int k0 = sub * 64;
#pragma unroll
        for (int c = 0; c < 4; c++) {
            uint4 xv = *(const uint4*)(ps + k0 + c * 16);
            uint4 yv = *(const uint4*)(pt + 256 + k0 + c * 16);
#pragma unroll
            for (int wd = 0; wd < 4; wd++) {
                unsigned int xw = ((const unsigned int*)&xv)[wd];
                unsigned int yw = ((const unsigned int*)&yv)[wd];
                f32x2 xl = __builtin_amdgcn_cvt_pk_f32_fp8(xw, false);
                f32x2 xh = __builtin_amdgcn_cvt_pk_f32_fp8(xw, true);
                f32x2 yl = __builtin_amdgcn_cvt_pk_f32_fp8(yw, false);
                f32x2 yh = __builtin_amdgcn_cvt_pk_f32_fp8(yw, true);
                int j = c * 16 + wd * 4;
                float4 bq = *(const float4*)(&b1r[sub][j]);
                float4 wq = *(const float4*)(&W2r[sub][j]);
                float h0 = fmaxf(xl[0] + yl[0] + bq.x, 0.f);
                float h1 = fmaxf(xl[1] + yl[1] + bq.y, 0.f);
                float h2 = fmaxf(xh[0] + yh[0] + bq.z, 0.f);
                float h3 = fmaxf(xh[1] + yh[1] + bq.w, 0.f);
                logit = fmaf(h0, wq.x, logit);
                logit = fmaf(h1, wq.y, logit);
                logit = fmaf(h2, wq.z, logit);
                logit = fmaf(h3, wq.w, logit);
            }
        }
        logit += __shfl_xor(logit, 1);
        logit += __shfl_xor(logit, 2);
        if (sub == 0) out_logits[g * 16 + e_in_w] = logit + b2v - pen;

        // ---- ha = relu(Xa[src]+Ya[tgt]+ba1) -> HA fp8 swizzled ----
        int ka = sub * 32;
        int habase = e_in_w * 128 + ka;
#pragma unroll
        for (int c = 0; c < 2; c++) {
            uint4 xv = *(const uint4*)(ps + 512 + ka + c * 16);
            uint4 yv = *(const uint4*)(pt + 640 + ka + c * 16);
            uint4 o;
#pragma unroll
            for (int wd = 0; wd < 4; wd++) {
                unsigned int xw = ((const unsigned int*)&xv)[wd];
                unsigned int yw = ((const unsigned int*)&yv)[wd];
                f32x2 xl = __builtin_amdgcn_cvt_pk_f32_fp8(xw, false);
                f32x2 xh = __builtin_amdgcn_cvt_pk_f32_fp8(xw, true);
                f32x2 yl = __builtin_amdgcn_cvt_pk_f32_fp8(yw, false);
                f32x2 yh = __builtin_amdgcn_cvt_pk_f32_fp8(yw, true);
                int j = c * 16 + wd * 4;
                float4 bq = *(const float4*)(&ba1r[sub][j]);
                float h0 = fmaxf(xl[0] + yl[0] + bq.x, 0.f);
                float h1 = fmaxf(xl[1] + yl[1] + bq.y, 0.f);
                float h2 = fmaxf(xh[0] + yh[0] + bq.z, 0.f);
                float h3 = fmaxf(xh[1] + yh[1] + bq.w, 0.f);
                unsigned int pk = __builtin_amdgcn_cvt_pk_fp8_f32(h0, h1, 0, false);
                pk = __builtin_amdgcn_cvt_pk_fp8_f32(h2, h3, pk, true);
                ((unsigned int*)&o)[wd] = pk;
            }
            *(uint4*)(HAc + ((habase + c * 16) ^ swz)) = o;
        }

        asm volatile("s_waitcnt lgkmcnt(0)" ::: "memory");
        __builtin_amdgcn_sched_barrier(0);

        // ---- army head: D(16x64) = HA(16x128) @ Wa2(128x64), fp8 MFMA ----
        f32x4 acc[4] = {};
        long af[4];
        int arow = lane & 15, g8 = lane >> 4;
        int rsw = (arow & 7) << 4;
#pragma unroll
        for (int ks = 0; ks < 4; ks++)
            af[ks] = *(const long*)(HAc + ((arow * 128 + ks * 32 + g8 * 8) ^ rsw));
#pragma unroll
        for (int nt = 0; nt < 4; nt++)
#pragma unroll
            for (int ks = 0; ks < 4; ks++) {
                long bfr = *(const long*)(wa2s + ((nt * 4 + ks) * 64 + lane) * 8);
                acc[nt] = __builtin_amdgcn_mfma_f32_16x16x32_fp8_fp8(af[ks], bfr, acc[nt], 0, 0, 0);
            }

        int e0 = g * 16;
#pragma unroll
        for (int q = 0; q < 4; q++) {
            int er = g8 * 4 + q;
            int saq = __shfl(sa, er * 4);
            size_t rowbase = (size_t)(e0 + er) * 64;
#pragma unroll
            for (int nt = 0; nt < 4; nt++) {
                int col = nt * 16 + (lane & 15);
                float v = acc[nt][q] + ba2v[nt];
                if (col >= saq) v = -1000000000.0f;
                out_army[rowbase + col] = v;
            }
        }

        ev = evn; sa = san; ta = tan;
    }
}

extern "C" void kernel_launch(void* const* d_in, const int* in_sizes, int n_in,
                              void* d_out, int out_size, void* d_ws, size_t ws_size,
                              hipStream_t stream) {
    const float* emb  = (const float*)d_in[0];
    const int*   edges= (const int*)d_in[1];
    const int*   army = (const int*)d_in[2];
    const float* W1   = (const float*)d_in[3];
    const float* b1   = (const float*)d_in[4];
    const float* W2   = (const float*)d_in[5];
    const float* b2   = (const float*)d_in[6];
    const float* Wa1  = (const float*)d_in[7];
    const float* ba1  = (const float*)d_in[8];
    const float* Wa2  = (const float*)d_in[9];
    const float* ba2  = (const float*)d_in[10];

    float* out_logits = (float*)d_out;
    float* out_army   = (float*)d_out + N_EDGES;

    // workspace layout (~77.2 MB)
    u16* wcatT  = (u16*)d_ws;                                   //    393,216 B
    u8*  Ptab   = (u8*)((char*)d_ws + 393216);                  // 76,800,000 B
    u8*  wa2f8  = (u8*)((char*)d_ws + 77193216);                //      8,192 B

    k_build_wcat<<<768, 256, 0, stream>>>(W1, Wa1, wcatT);
    k_build_wa2frag<<<16, 64, 0, stream>>>(Wa2, wa2f8);
    k_gemm<<<8 * TPX, 256, 0, stream>>>(emb, wcatT, Ptab);
    k_edges<<<1280, 256, 0, stream>>>(Ptab, wa2f8, edges, army, b1, W2, b2, ba1, ba2,
                                      out_logits, out_army);
}

// Round 11
// 181.231 us; speedup vs baseline: 1.2879x; 1.2879x over previous
//
#include <hip/hip_runtime.h>
#include <stdint.h>

typedef unsigned short u16;
typedef unsigned char u8;
typedef __attribute__((ext_vector_type(8))) short bf16x8;
typedef __attribute__((ext_vector_type(4))) float f32x4;
typedef __attribute__((ext_vector_type(2))) float f32x2;
typedef __attribute__((ext_vector_type(8))) unsigned short u16x8;

#define N_NODES 100000
#define N_EDGES 500000
#define EMBED   256
#define PDIM    768   // fp8 bytes: X[0:256) Y[256:512) Xa[512:640) Ya[640:768)
#define NG16    (N_EDGES / 16)   // 31250 wave-groups of 16 edges
#define NTILES  4692             // 782 m-tiles * 6 n-tiles
#define TPX     587              // ceil(4692/8) tiles per XCD

__device__ __forceinline__ u16 f2bf(float f) {
    unsigned int x; __builtin_memcpy(&x, &f, 4);
    unsigned int r = (x + 0x7fffu + ((x >> 16) & 1u)) >> 16;
    return (u16)r;
}

#define GLOBAL_AS __attribute__((address_space(1)))
#define LDS_AS    __attribute__((address_space(3)))
__device__ __forceinline__ void gload_lds16(const void* g, void* l) {
    __builtin_amdgcn_global_load_lds((const GLOBAL_AS uint32_t*)g,
                                     (LDS_AS uint32_t*)l, 16, 0, 0);
}

// ---------------- K0a: emb fp32 -> bf16 ----------------
__global__ __launch_bounds__(256) void k_convert_emb(const float* __restrict__ emb,
                                                     u16* __restrict__ out, int n8) {
    int i = blockIdx.x * 256 + threadIdx.x;
    if (i >= n8) return;
    const float4* p = (const float4*)emb + (size_t)i * 2;
    float4 a = p[0], b = p[1];
    u16x8 o;
    o[0] = f2bf(a.x); o[1] = f2bf(a.y); o[2] = f2bf(a.z); o[3] = f2bf(a.w);
    o[4] = f2bf(b.x); o[5] = f2bf(b.y); o[6] = f2bf(b.z); o[7] = f2bf(b.w);
    *(u16x8*)(out + (size_t)i * 8) = o;
}

// ---------------- K0b: build WcatT [768][256] bf16 ----------------
__global__ __launch_bounds__(256) void k_build_wcat(const float* __restrict__ W1,
                                                    const float* __restrict__ Wa1,
                                                    u16* __restrict__ WcatT) {
    int c = blockIdx.x;
    int k = threadIdx.x;
    float v;
    if (c < 256)      v = W1[(size_t)k * 256 + c];
    else if (c < 512) v = W1[(size_t)(256 + k) * 256 + (c - 256)];
    else if (c < 640) v = Wa1[(size_t)k * 128 + (c - 512)];
    else              v = Wa1[(size_t)(256 + k) * 128 + (c - 640)];
    WcatT[(size_t)c * 256 + k] = f2bf(v);
}

// ---------------- K0c: Wa2 -> fp8 B-fragment table [16 frags][64 lanes][8B] ----------------
__global__ __launch_bounds__(64) void k_build_wa2frag(const float* __restrict__ Wa2,
                                                      u8* __restrict__ out) {
    int f = blockIdx.x, l = threadIdx.x;
    int nt = f >> 2, ks = f & 3;
    int j = nt * 16 + (l & 15);
    int kb = ks * 32 + (l >> 4) * 8;
    float v[8];
#pragma unroll
    for (int e = 0; e < 8; e++) v[e] = Wa2[(size_t)(kb + e) * 64 + j];
    unsigned int w0 = __builtin_amdgcn_cvt_pk_fp8_f32(v[0], v[1], 0, false);
    w0 = __builtin_amdgcn_cvt_pk_fp8_f32(v[2], v[3], w0, true);
    unsigned int w1 = __builtin_amdgcn_cvt_pk_fp8_f32(v[4], v[5], 0, false);
    w1 = __builtin_amdgcn_cvt_pk_fp8_f32(v[6], v[7], w1, true);
    uint2 o; o.x = w0; o.y = w1;
    *(uint2*)(out + ((size_t)f * 64 + l) * 8) = o;
}

// ---------------- K1: P[100000][768] fp8 = emb_bf16 @ Wcat ----------------
// XCD-chunked tile remap: the 6 n-tiles of each m-tile run on the same XCD
// so the A-tile is fetched from HBM once and L2-hits 5 times.
__global__ __launch_bounds__(256) void k_gemm(const u16* __restrict__ A,
                                              const u16* __restrict__ BT,
                                              u8* __restrict__ P) {
    __shared__ u16 As[128 * 64];
    __shared__ u16 Bs[128 * 64];
    int lid = (blockIdx.x & 7) * TPX + (blockIdx.x >> 3);
    if (lid >= NTILES) return;
    int mtile = lid / 6, ntile = lid % 6;
    int m0 = mtile * 128, n0 = ntile * 128;
    int t = threadIdx.x, w = t >> 6, lane = t & 63;
    int wr = (w >> 1) * 64, wc = (w & 1) * 64;

    f32x4 acc[4][4] = {};

    for (int kk = 0; kk < 256; kk += 64) {
#pragma unroll
        for (int i = 0; i < 4; i++) {
            int q = w * 4 + i;
            int row = 8 * q + (lane >> 3);
            int kcol = (lane & 7) * 8;
            int arow = m0 + row; if (arow > N_NODES - 1) arow = N_NODES - 1;
            gload_lds16(A + (size_t)arow * 256 + kk + kcol, As + q * 512);
            gload_lds16(BT + (size_t)(n0 + row) * 256 + kk + kcol, Bs + q * 512);
        }
        __syncthreads();

        bf16x8 af[4][2], bf[4][2];
#pragma unroll
        for (int ks = 0; ks < 2; ks++) {
#pragma unroll
            for (int m = 0; m < 4; m++)
                af[m][ks] = *(const bf16x8*)(As + (wr + m * 16 + (lane & 15)) * 64 + ks * 32 + (lane >> 4) * 8);
#pragma unroll
            for (int n = 0; n < 4; n++)
                bf[n][ks] = *(const bf16x8*)(Bs + (wc + n * 16 + (lane & 15)) * 64 + ks * 32 + (lane >> 4) * 8);
        }
#pragma unroll
        for (int m = 0; m < 4; m++)
#pragma unroll
            for (int n = 0; n < 4; n++)
#pragma unroll
                for (int ks = 0; ks < 2; ks++)
                    acc[m][n] = __builtin_amdgcn_mfma_f32_16x16x32_bf16(af[m][ks], bf[n][ks], acc[m][n], 0, 0, 0);
        __syncthreads();
    }

#pragma unroll
    for (int m = 0; m < 4; m++) {
        int rbase = m0 + wr + m * 16 + (lane >> 4) * 4;
#pragma unroll
        for (int q = 0; q < 4; q++) {
            int row = rbase + q;
            if (row >= N_NODES) continue;
            u8* prow = P + (size_t)row * 768 + n0 + wc + (lane & 15);
#pragma unroll
            for (int n = 0; n < 4; n++) {
                int pk = __builtin_amdgcn_cvt_pk_fp8_f32(acc[m][n][q], acc[m][n][q], 0, false);
                prow[n * 16] = (u8)(pk & 0xff);
            }
        }
    }
}

// ---------------- K2: fused per-edge kernel (round-6 proven configuration) ----------------
__global__ __launch_bounds__(256, 5) void k_edges(const u8* __restrict__ Ptab,
                                                  const u8* __restrict__ wa2t,
                                                  const int* __restrict__ edges,
                                                  const int* __restrict__ army,
                                                  const float* __restrict__ b1,
                                                  const float* __restrict__ W2,
                                                  const float* __restrict__ b2,
                                                  const float* __restrict__ ba1,
                                                  const float* __restrict__ ba2,
                                                  float* __restrict__ out_logits,
                                                  float* __restrict__ out_army) {
    __shared__ u8 wa2s[8192];            // fp8 B-frag table, shared by all waves
    __shared__ u8 HA[4][16 * 128];       // fp8 per-wave, row-XOR swizzled (2KB/wave)
    // per-sub replicated bias tables; row strides 68/36 floats => subs land on
    // distinct 4-bank groups => conflict-free broadcast reads
    __shared__ float b1r[4][68], W2r[4][68], ba1r[4][36];

    int t = threadIdx.x, w = t >> 6, lane = t & 63;

    b1r[t >> 6][t & 63] = b1[t];
    W2r[t >> 6][t & 63] = W2[t];
    if (t < 128) ba1r[t >> 5][t & 31] = ba1[t];
    {   // copy 8KB wa2 frag table global->LDS
        uint4* dst = (uint4*)wa2s; const uint4* src = (const uint4*)wa2t;
        dst[t] = src[t]; dst[t + 256] = src[t + 256];
    }
    float b2v = b2[0];
    float ba2v[4];
#pragma unroll
    for (int nt = 0; nt < 4; nt++) ba2v[nt] = ba2[nt * 16 + (lane & 15)];
    __syncthreads();   // once, outside the loop

    char* HAc = (char*)HA[w];
    int e_in_w = lane >> 2, sub = lane & 3;
    int swz = (e_in_w & 7) << 4;
    int gstep = gridDim.x << 2;

    int g = blockIdx.x * 4 + w;
    int2 ev = {0, 0}; int sa = 0, ta = 0;
    if (g < NG16) {
        ev = *(const int2*)(edges + 2 * (g * 16 + e_in_w));
        sa = army[ev.x]; ta = army[ev.y];
    }

    for (; g < NG16; g += gstep) {
        // prefetch next iteration's edge + army (breaks the serial pointer chain)
        int gn = g + gstep;
        int2 evn = ev; int san = sa, tan = ta;
        if (gn < NG16) {
            evn = *(const int2*)(edges + 2 * (gn * 16 + e_in_w));
            san = army[evn.x]; tan = army[evn.y];
        }

        float pen = ((sa <= 2) || (ta >= 3 * sa)) ? 1.0f : 0.0f;
        if (ev.x == ev.y) pen += 100.0f;
        const u8* ps = Ptab + (size_t)ev.x * 768;
        const u8* pt = Ptab + (size_t)ev.y * 768;

        // ---- edge logit over k = sub*64 .. +64 (interleaved load/consume) ----
        float logit = 0.f;
        int k0 = sub * 64;
#pragma unroll
        for (int c = 0; c < 4; c++) {
            uint4 xv = *(const uint4*)(ps + k0 + c * 16);
            uint4 yv = *(const uint4*)(pt + 256 + k0 + c * 16);
#pragma unroll
            for (int wd = 0; wd < 4; wd++) {
                unsigned int xw = ((const unsigned int*)&xv)[wd];
                unsigned int yw = ((const unsigned int*)&yv)[wd];
                f32x2 xl = __builtin_amdgcn_cvt_pk_f32_fp8(xw, false);
                f32x2 xh = __builtin_amdgcn_cvt_pk_f32_fp8(xw, true);
                f32x2 yl = __builtin_amdgcn_cvt_pk_f32_fp8(yw, false);
                f32x2 yh = __builtin_amdgcn_cvt_pk_f32_fp8(yw, true);
                int j = c * 16 + wd * 4;
                float4 bq = *(const float4*)(&b1r[sub][j]);
                float4 wq = *(const float4*)(&W2r[sub][j]);
                float h0 = fmaxf(xl[0] + yl[0] + bq.x, 0.f);
                float h1 = fmaxf(xl[1] + yl[1] + bq.y, 0.f);
                float h2 = fmaxf(xh[0] + yh[0] + bq.z, 0.f);
                float h3 = fmaxf(xh[1] + yh[1] + bq.w, 0.f);
                logit = fmaf(h0, wq.x, logit);
                logit = fmaf(h1, wq.y, logit);
                logit = fmaf(h2, wq.z, logit);
                logit = fmaf(h3, wq.w, logit);
            }
        }
        logit += __shfl_xor(logit, 1);
        logit += __shfl_xor(logit, 2);
        if (sub == 0) out_logits[g * 16 + e_in_w] = logit + b2v - pen;

        // ---- ha = relu(Xa[src]+Ya[tgt]+ba1) -> HA fp8 swizzled ----
        int ka = sub * 32;
        int habase = e_in_w * 128 + ka;
#pragma unroll
        for (int c = 0; c < 2; c++) {
            uint4 xv = *(const uint4*)(ps + 512 + ka + c * 16);
            uint4 yv = *(const uint4*)(pt + 640 + ka + c * 16);
            uint4 o;
#pragma unroll
            for (int wd = 0; wd < 4; wd++) {
                unsigned int xw = ((const unsigned int*)&xv)[wd];
                unsigned int yw = ((const unsigned int*)&yv)[wd];
                f32x2 xl = __builtin_amdgcn_cvt_pk_f32_fp8(xw, false);
                f32x2 xh = __builtin_amdgcn_cvt_pk_f32_fp8(xw, true);
                f32x2 yl = __builtin_amdgcn_cvt_pk_f32_fp8(yw, false);
                f32x2 yh = __builtin_amdgcn_cvt_pk_f32_fp8(yw, true);
                int j = c * 16 + wd * 4;
                float4 bq = *(const float4*)(&ba1r[sub][j]);
                float h0 = fmaxf(xl[0] + yl[0] + bq.x, 0.f);
                float h1 = fmaxf(xl[1] + yl[1] + bq.y, 0.f);
                float h2 = fmaxf(xh[0] + yh[0] + bq.z, 0.f);
                float h3 = fmaxf(xh[1] + yh[1] + bq.w, 0.f);
                unsigned int pk = __builtin_amdgcn_cvt_pk_fp8_f32(h0, h1, 0, false);
                pk = __builtin_amdgcn_cvt_pk_fp8_f32(h2, h3, pk, true);
                ((unsigned int*)&o)[wd] = pk;
            }
            *(uint4*)(HAc + ((habase + c * 16) ^ swz)) = o;
        }

        asm volatile("s_waitcnt lgkmcnt(0)" ::: "memory");
        __builtin_amdgcn_sched_barrier(0);

        // ---- army head: D(16x64) = HA(16x128) @ Wa2(128x64), fp8 MFMA ----
        f32x4 acc[4] = {};
        long af[4];
        int arow = lane & 15, g8 = lane >> 4;
        int rsw = (arow & 7) << 4;
#pragma unroll
        for (int ks = 0; ks < 4; ks++)
            af[ks] = *(const long*)(HAc + ((arow * 128 + ks * 32 + g8 * 8) ^ rsw));
#pragma unroll
        for (int nt = 0; nt < 4; nt++)
#pragma unroll
            for (int ks = 0; ks < 4; ks++) {
                long bfr = *(const long*)(wa2s + ((nt * 4 + ks) * 64 + lane) * 8);
                acc[nt] = __builtin_amdgcn_mfma_f32_16x16x32_fp8_fp8(af[ks], bfr, acc[nt], 0, 0, 0);
            }

        int e0 = g * 16;
#pragma unroll
        for (int q = 0; q < 4; q++) {
            int er = g8 * 4 + q;
            int saq = __shfl(sa, er * 4);
            size_t rowbase = (size_t)(e0 + er) * 64;
#pragma unroll
            for (int nt = 0; nt < 4; nt++) {
                int col = nt * 16 + (lane & 15);
                float v = acc[nt][q] + ba2v[nt];
                if (col >= saq) v = -1000000000.0f;
                out_army[rowbase + col] = v;
            }
        }

        ev = evn; sa = san; ta = tan;
    }
}

extern "C" void kernel_launch(void* const* d_in, const int* in_sizes, int n_in,
                              void* d_out, int out_size, void* d_ws, size_t ws_size,
                              hipStream_t stream) {
    const float* emb  = (const float*)d_in[0];
    const int*   edges= (const int*)d_in[1];
    const int*   army = (const int*)d_in[2];
    const float* W1   = (const float*)d_in[3];
    const float* b1   = (const float*)d_in[4];
    const float* W2   = (const float*)d_in[5];
    const float* b2   = (const float*)d_in[6];
    const float* Wa1  = (const float*)d_in[7];
    const float* ba1  = (const float*)d_in[8];
    const float* Wa2  = (const float*)d_in[9];
    const float* ba2  = (const float*)d_in[10];

    float* out_logits = (float*)d_out;
    float* out_army   = (float*)d_out + N_EDGES;

    // workspace layout (~128.4 MB)
    u16* emb_bf = (u16*)d_ws;                                   // 51,200,000 B
    u16* wcatT  = (u16*)((char*)d_ws + 51200000);               //    393,216 B
    u8*  Ptab   = (u8*)((char*)d_ws + 51593216);                //  76,800,000 B
    u8*  wa2f8  = (u8*)((char*)d_ws + 128393216);               //      8,192 B

    int n8 = (N_NODES * EMBED) / 8;
    k_convert_emb<<<(n8 + 255) / 256, 256, 0, stream>>>(emb, emb_bf, n8);
    k_build_wcat<<<768, 256, 0, stream>>>(W1, Wa1, wcatT);
    k_build_wa2frag<<<16, 64, 0, stream>>>(Wa2, wa2f8);
    k_gemm<<<8 * TPX, 256, 0, stream>>>(emb_bf, wcatT, Ptab);
    k_edges<<<1280, 256, 0, stream>>>(Ptab, wa2f8, edges, army, b1, W2, b2, ba1, ba2,
                                      out_logits, out_army);
}